// Round 6
// baseline (393.273 us; speedup 1.0000x reference)
//
#include <hip/hip_runtime.h>
#include <hip/hip_bf16.h>

#define SQL  2048
#define DM   256
#define LNEPS 1e-6f
#define LOG2E    (1.44269504f)

// ---- workspace layout (byte offsets) ----
#define B_XB    (0ull)            // 4 MB  x bf16 [8192][256]
#define B_QB    (4ull<<20)        // 4 MB  q bf16 [bh][s][32]  (pre-scaled by log2e)
#define B_KB    (8ull<<20)        // 4 MB  k bf16 [bh][s][32]
#define B_VT    (12ull<<20)       // 4 MB  V^T bf16 [bh][32][2048] LINEAR
#define B_CTX   (16ull<<20)       // 4 MB  ctx bf16 [8192][256]
#define B_O1B   (20ull<<20)       // 4 MB  out1 bf16
#define B_O1F   (24ull<<20)       // 8 MB  out1 f32
#define B_MID   (32ull<<20)       // 16 MB mid bf16 [8192][1024]; ALSO c1 partials (2x8MB)
#define B_WQKVT (48ull<<20)       // 384 KB bf16 [768][256]
#define B_WOT   ((48ull<<20)+(512ull<<10))  // 128 KB
#define B_W1T   (49ull<<20)       // 512 KB bf16 [1024][256]
#define B_W2T   ((49ull<<20)+(512ull<<10))  // 512 KB bf16 [256][1024]
#define B_BQKV  (50ull<<20)       // 3 KB f32
#define B_HQ    ((50ull<<20)+(64ull<<10))   // 256 KB u32 packed {1.0,hq}
#define B_HK    ((50ull<<20)+(320ull<<10))  // 256 KB u32 packed {hk,1.0}
#define B_C2    (0ull)            // 16 MB f32 partials (alias xb/qb/kb/vt, dead)

typedef float  f32x16 __attribute__((ext_vector_type(16)));
typedef short  bf16x8 __attribute__((ext_vector_type(8)));
typedef int    i32x4  __attribute__((ext_vector_type(4)));
typedef int    i32x2  __attribute__((ext_vector_type(2)));

static __device__ __forceinline__ unsigned short bfu(float f){
    __hip_bfloat16 h = __float2bfloat16(f);
    return *reinterpret_cast<unsigned short*>(&h);
}
static __device__ __forceinline__ unsigned pk2(float a, float b){
    return (unsigned)bfu(a) | ((unsigned)bfu(b) << 16);
}
static __device__ __forceinline__ void glds16(const void* g, void* l){
    __builtin_amdgcn_global_load_lds((const __attribute__((address_space(1))) unsigned int*)g,
                                     (__attribute__((address_space(3))) unsigned int*)l, 16, 0, 0);
}

// ---------------- fused packing: weights->bf16^T, biases, x->bf16 ----------------
__global__ __launch_bounds__(256) void k_packall(
    const float* __restrict__ wq, const float* __restrict__ wk, const float* __restrict__ wv,
    const float* __restrict__ wo, const float* __restrict__ w1, const float* __restrict__ w2,
    const float* __restrict__ bq, const float* __restrict__ bk, const float* __restrict__ bv,
    const float* __restrict__ x,
    unsigned short* __restrict__ wqkvT, unsigned short* __restrict__ woT,
    unsigned short* __restrict__ w1T, unsigned short* __restrict__ w2T,
    float* __restrict__ bqkv, unsigned short* __restrict__ xb)
{
    __shared__ float tile[32][33];
    const int bid = blockIdx.x;
    const int t = threadIdx.x;
    if (bid < 768) {
        const float* W; unsigned short* Wt; int K, N, xk, yn;
        if (bid < 192) {
            int which = bid >> 6, local = bid & 63;
            W = (which == 0) ? wq : (which == 1 ? wk : wv);
            Wt = wqkvT + which * 65536; K = 256; N = 256;
            xk = local & 7; yn = local >> 3;
        } else if (bid < 256) {
            int local = bid - 192; W = wo; Wt = woT; K = 256; N = 256;
            xk = local & 7; yn = local >> 3;
        } else if (bid < 512) {
            int local = bid - 256; W = w1; Wt = w1T; K = 256; N = 1024;
            xk = local & 7; yn = local >> 3;
        } else {
            int local = bid - 512; W = w2; Wt = w2T; K = 1024; N = 256;
            xk = local & 31; yn = local >> 5;
        }
        const int tx = t & 31, ty = t >> 5;
        const int kb = xk * 32, nb = yn * 32;
#pragma unroll
        for (int i = 0; i < 32; i += 8) tile[ty + i][tx] = W[(size_t)(kb + ty + i) * N + nb + tx];
        __syncthreads();
#pragma unroll
        for (int i = 0; i < 32; i += 8) Wt[(size_t)(nb + ty + i) * K + kb + tx] = bfu(tile[tx][ty + i]);
    } else if (bid < 771) {
        int wb = bid - 768;
        const float* s = (wb == 0) ? bq : (wb == 1 ? bk : bv);
        bqkv[wb * 256 + t] = s[t];
    } else {
        const int i = (bid - 771) * 256 + t;
        float4 v = ((const float4*)x)[i];
        ushort4 o; o.x = bfu(v.x); o.y = bfu(v.y); o.z = bfu(v.z); o.w = bfu(v.w);
        ((ushort4*)xb)[i] = o;
    }
}

// ---------------- QKV GEMM (2-phase dbuf): q scaled by log2e; v -> VT linear ----------------
__global__ __launch_bounds__(256, 2) void k_qkv(
    const unsigned short* __restrict__ A, const unsigned short* __restrict__ Bt,
    const float* __restrict__ bias,
    unsigned short* __restrict__ qb, unsigned short* __restrict__ kb,
    unsigned short* __restrict__ vtg)
{
    __shared__ __align__(16) char smem[65536];
    const int t = threadIdx.x;
    const int lane = t & 63, w = t >> 6;
    const int lo = lane & 31, hi = lane >> 5;
    const int row0 = blockIdx.x * 128;
    const int col0 = blockIdx.y * 128;
    f32x16 acc[2][2] = {};
    const int gS = lane & 7;
    const int rr = w * 32 + (lane >> 3);

    auto stage = [&](int buf, int kt) {
        const int k0 = kt * 64;
        char* As = smem + buf * 32768;
        char* Bs = As + 16384;
#pragma unroll
        for (int i = 0; i < 4; ++i) {
            const int r = rr + i * 8;
            glds16((const char*)(A  + (size_t)(row0 + r) * 256 + k0) + ((gS ^ (r & 7)) << 4),
                   As + w * 4096 + i * 1024 + lane * 16);
            glds16((const char*)(Bt + (size_t)(col0 + r) * 256 + k0) + ((gS ^ (r & 7)) << 4),
                   Bs + w * 4096 + i * 1024 + lane * 16);
        }
    };

    stage(0, 0);
    __syncthreads();
    for (int kt = 0; kt < 4; ++kt) {
        if (kt + 1 < 4) stage((kt + 1) & 1, kt + 1);
        const char* As = smem + (kt & 1) * 32768;
        const char* Bs = As + 16384;
        const int rA = (w >> 1) * 64 + lo;
        const int rB = (w & 1) * 64 + lo;
#pragma unroll
        for (int s = 0; s < 4; ++s) {
            const int g = s * 2 + hi;
            bf16x8 fa0 = *(const bf16x8*)(As + rA * 128 + ((g ^ (rA & 7)) << 4));
            bf16x8 fa1 = *(const bf16x8*)(As + (rA + 32) * 128 + ((g ^ (rA & 7)) << 4));
            bf16x8 fb0 = *(const bf16x8*)(Bs + rB * 128 + ((g ^ (rB & 7)) << 4));
            bf16x8 fb1 = *(const bf16x8*)(Bs + (rB + 32) * 128 + ((g ^ (rB & 7)) << 4));
            acc[0][0] = __builtin_amdgcn_mfma_f32_32x32x16_bf16(fa0, fb0, acc[0][0], 0, 0, 0);
            acc[0][1] = __builtin_amdgcn_mfma_f32_32x32x16_bf16(fa0, fb1, acc[0][1], 0, 0, 0);
            acc[1][0] = __builtin_amdgcn_mfma_f32_32x32x16_bf16(fa1, fb0, acc[1][0], 0, 0, 0);
            acc[1][1] = __builtin_amdgcn_mfma_f32_32x32x16_bf16(fa1, fb1, acc[1][1], 0, 0, 0);
        }
        __syncthreads();
    }
#pragma unroll
    for (int m = 0; m < 2; ++m)
#pragma unroll
    for (int n = 0; n < 2; ++n) {
        const int c0 = col0 + (w & 1) * 64 + n * 32;
        const int which = c0 >> 8, h = (c0 >> 5) & 7;
        const float bv = bias[c0 + lo];
        if (which < 2) {
            unsigned short* dst = (which == 0) ? qb : kb;
            const float scl = (which == 0) ? LOG2E : 1.0f;
#pragma unroll
            for (int r = 0; r < 16; ++r) {
                const int gr = row0 + (w >> 1) * 64 + m * 32 + (r & 3) + 8 * (r >> 2) + 4 * hi;
                const int b = gr >> 11, s = gr & 2047;
                dst[(((size_t)(b * 8 + h)) * SQL + s) * 32 + lo] = bfu((acc[m][n][r] + bv) * scl);
            }
        } else {
            // V -> VT[bh][d=lo][s] linear
#pragma unroll
            for (int r = 0; r < 16; ++r) {
                const int gr = row0 + (w >> 1) * 64 + m * 32 + (r & 3) + 8 * (r >> 2) + 4 * hi;
                const int b = gr >> 11, s = gr & 2047;
                vtg[((size_t)(b * 8 + h)) * 65536 + (size_t)lo * 2048 + s] = bfu(acc[m][n][r] + bv);
            }
        }
    }
}

// ---------------- hq/hk packed as ready MFMA fragment words ----------------
__global__ __launch_bounds__(256) void k_h2(const unsigned short* __restrict__ qb,
                                            const unsigned short* __restrict__ kb,
                                            unsigned int* __restrict__ hqp,
                                            unsigned int* __restrict__ hkp)
{
    const int gid = blockIdx.x * 256 + threadIdx.x;
    const unsigned short* qp = qb + (size_t)gid * 32;
    const unsigned short* kp = kb + (size_t)gid * 32;
    float sq = 0.f, sk = 0.f;
#pragma unroll
    for (int i = 0; i < 4; ++i) {
        i32x4 qv = *(const i32x4*)(qp + i * 8);
        i32x4 kv = *(const i32x4*)(kp + i * 8);
#pragma unroll
        for (int j = 0; j < 4; ++j) {
            unsigned int qw = (unsigned int)qv[j], kw = (unsigned int)kv[j];
            float a = __builtin_bit_cast(float, qw << 16);
            float c = __builtin_bit_cast(float, qw & 0xffff0000u);
            float d = __builtin_bit_cast(float, kw << 16);
            float e = __builtin_bit_cast(float, kw & 0xffff0000u);
            sq += a * a + c * c; sk += d * d + e * e;
        }
    }
    // hq' = -0.5/log2e*||log2e q||^2 + log2(log2e); q was pre-scaled by log2e
    const float hq = -0.34657359f * sq + 0.52876637f;
    const float hk = -0.72134752f * sk;
    hqp[gid] = 0x3F80u | ((unsigned)bfu(hq) << 16);        // B3: {k0:1.0, k1:hq}
    hkp[gid] = (unsigned)bfu(hk) | 0x3F800000u;            // A3: {k0:hk,  k1:1.0}
}

// ---------------- MFMA attention: direct-from-L2, no LDS staging, no loop barriers ----------------
// Tile-row permutation pi(m) = swap bits 2,3 of m (applied to K-load side) makes each
// PV B-frag a contiguous 16B V^T read. S^T = mfma(K,Q^T); w = exp2(exp2(sc)).
__global__ __launch_bounds__(512, 4) void k_attn(
    const unsigned short* __restrict__ qg, const unsigned short* __restrict__ kg,
    const unsigned short* __restrict__ vtg, const unsigned int* __restrict__ hqp,
    const unsigned int* __restrict__ hkp, unsigned short* __restrict__ ctxb)
{
    __shared__ __align__(16) float redacc[3 * 16 * 128];
    __shared__ __align__(16) float redden[3 * 128];
    __shared__ __align__(16) float invs[64];

    const int t = threadIdx.x;
    const int grp = t >> 7;          // 0..3 key-group (512 keys each)
    const int tl  = t & 127;
    const int lane = t & 63;
    const int w   = (t >> 6) & 1;    // q sub-block wave
    const int lo = lane & 31;
    const int hi = lane >> 5;

    const int bid = blockIdx.x;
    const int qc = bid & 31;
    const int bh = bid >> 5;

    const int qrow = qc * 64 + w * 32 + lo;
    const unsigned short* qp = qg + ((size_t)bh * SQL + qrow) * 32;
    const bf16x8 qf0 = *(const bf16x8*)(qp + hi * 8);
    const bf16x8 qf1 = *(const bf16x8*)(qp + 16 + hi * 8);
    i32x4 b3i = {};
    if (hi == 0) b3i[0] = (int)hqp[(size_t)bh * SQL + qrow];
    const bf16x8 b3 = __builtin_bit_cast(bf16x8, b3i);

    const int plo = (lo & 19) | ((lo & 4) << 1) | ((lo & 8) >> 1);   // swap bits 2,3
    const unsigned short* kbase = kg + (size_t)bh * SQL * 32;
    const unsigned short* vbase = vtg + (size_t)bh * 65536 + (size_t)lo * 2048;
    const unsigned int*   hkb   = hkp + (size_t)bh * SQL;

    f32x16 acc = {};
    float den = 0.f;

    // step s = 0..15: keys [grp*512 + s*32, +32)
#define LD(s, KF0, KF1, A3, VB0, VB1)                                              \
    {                                                                              \
        const int kb_ = grp * 512 + (s) * 32;                                      \
        const int gk_ = kb_ + plo;                                                 \
        KF0 = *(const i32x4*)(kbase + (size_t)gk_ * 32 + hi * 8);                  \
        KF1 = *(const i32x4*)(kbase + (size_t)gk_ * 32 + 16 + hi * 8);             \
        A3 = i32x4{};                                                              \
        if (hi == 0) A3[0] = (int)hkb[gk_];                                        \
        VB0 = *(const i32x4*)(vbase + kb_ + 8 * hi);                               \
        VB1 = *(const i32x4*)(vbase + kb_ + 16 + 8 * hi);                          \
    }

    i32x4 kf0a, kf1a, a3a, vb0a, vb1a;
    i32x4 kf0b, kf1b, a3b, vb0b, vb1b;
    LD(0, kf0a, kf1a, a3a, vb0a, vb1a);
#pragma unroll
    for (int s = 0; s < 16; ++s) {
        // issue next step's loads first (hide L2 latency under compute)
        if (s + 1 < 16) {
            if (s & 1) { LD(s + 1, kf0a, kf1a, a3a, vb0a, vb1a); }
            else       { LD(s + 1, kf0b, kf1b, a3b, vb0b, vb1b); }
        }
        const i32x4 kf0 = (s & 1) ? kf0b : kf0a;
        const i32x4 kf1 = (s & 1) ? kf1b : kf1a;
        const i32x4 a3  = (s & 1) ? a3b  : a3a;
        const i32x4 vb0 = (s & 1) ? vb0b : vb0a;
        const i32x4 vb1 = (s & 1) ? vb1b : vb1a;

        f32x16 sc = {};
        sc = __builtin_amdgcn_mfma_f32_32x32x16_bf16(__builtin_bit_cast(bf16x8, kf0), qf0, sc, 0, 0, 0);
        sc = __builtin_amdgcn_mfma_f32_32x32x16_bf16(__builtin_bit_cast(bf16x8, kf1), qf1, sc, 0, 0, 0);
        sc = __builtin_amdgcn_mfma_f32_32x32x16_bf16(__builtin_bit_cast(bf16x8, a3), b3, sc, 0, 0, 0);
        float wv[16];
#pragma unroll
        for (int r = 0; r < 16; ++r) {
            float e1 = __builtin_amdgcn_exp2f(sc[r]);   // = log2e * exp(-0.5 d)
            float ww = __builtin_amdgcn_exp2f(e1);      // = e^{exp(-0.5 d)}
            den += ww;
            wv[r] = ww;
        }
        i32x4 p0; p0[0]=pk2(wv[0],wv[1]);   p0[1]=pk2(wv[2],wv[3]);
                  p0[2]=pk2(wv[4],wv[5]);   p0[3]=pk2(wv[6],wv[7]);
        i32x4 p1; p1[0]=pk2(wv[8],wv[9]);   p1[1]=pk2(wv[10],wv[11]);
                  p1[2]=pk2(wv[12],wv[13]); p1[3]=pk2(wv[14],wv[15]);
        acc = __builtin_amdgcn_mfma_f32_32x32x16_bf16(
            __builtin_bit_cast(bf16x8, p0), __builtin_bit_cast(bf16x8, vb0), acc, 0, 0, 0);
        acc = __builtin_amdgcn_mfma_f32_32x32x16_bf16(
            __builtin_bit_cast(bf16x8, p1), __builtin_bit_cast(bf16x8, vb1), acc, 0, 0, 0);
    }
#undef LD

    // ---- cross-group tree reduction ----
    if (grp != 0) {
#pragma unroll
        for (int r = 0; r < 16; ++r) redacc[((grp - 1) * 16 + r) * 128 + tl] = acc[r];
        redden[(grp - 1) * 128 + tl] = den;
    }
    __syncthreads();
    if (grp == 0) {
#pragma unroll
        for (int r = 0; r < 16; ++r)
            acc[r] += redacc[r * 128 + tl] + redacc[(16 + r) * 128 + tl] + redacc[(32 + r) * 128 + tl];
        den += redden[tl] + redden[128 + tl] + redden[256 + tl];
        const float dfull = den + __shfl_xor(den, 32);
        if (hi == 0) invs[w * 32 + lo] = 1.f / dfull;
        // same-wave LDS write->read, no barrier needed
        float4 i0 = *(const float4*)&invs[w * 32 + 4 * hi];
        float4 i1 = *(const float4*)&invs[w * 32 + 8 + 4 * hi];
        float4 i2 = *(const float4*)&invs[w * 32 + 16 + 4 * hi];
        float4 i3 = *(const float4*)&invs[w * 32 + 24 + 4 * hi];
        float iv[16] = {i0.x,i0.y,i0.z,i0.w, i1.x,i1.y,i1.z,i1.w,
                        i2.x,i2.y,i2.z,i2.w, i3.x,i3.y,i3.z,i3.w};
        const int b = bh >> 3, h = bh & 7;
        unsigned short* cbase = ctxb + ((size_t)(b * SQL + qc * 64 + w * 32)) * 256 + h * 32 + lo;
#pragma unroll
        for (int r = 0; r < 16; ++r) {
            const int qr = (r & 3) + 8 * (r >> 2) + 4 * hi;
            cbase[(size_t)qr * 256] = bfu(acc[r] * iv[r]);
        }
    }
}

// ---------------- generic MFMA GEMM, 2-phase dbuf, split-K via blockIdx.z ----------------
template<int KSTRIDE, int KT, int NFULL, int RELU, int OUTF, int OUTB>
__global__ __launch_bounds__(256, 2) void k_gemm(
    const unsigned short* __restrict__ A, const unsigned short* __restrict__ Bt,
    const float* __restrict__ bias,
    float* __restrict__ outf, unsigned short* __restrict__ outb)
{
    __shared__ __align__(16) char smem[65536];
    const int t = threadIdx.x;
    const int lane = t & 63, w = t >> 6;
    const int lo = lane & 31, hi = lane >> 5;
    const int row0 = blockIdx.x * 128;
    const int col0 = blockIdx.y * 128;
    const int z = blockIdx.z;
    f32x16 acc[2][2] = {};
    const int gS = lane & 7;
    const int rr = w * 32 + (lane >> 3);

    auto stage = [&](int buf, int kt) {
        const int k0 = (z * KT + kt) * 64;
        char* As = smem + buf * 32768;
        char* Bs = As + 16384;
#pragma unroll
        for (int i = 0; i < 4; ++i) {
            const int r = rr + i * 8;
            glds16((const char*)(A  + (size_t)(row0 + r) * KSTRIDE + k0) + ((gS ^ (r & 7)) << 4),
                   As + w * 4096 + i * 1024 + lane * 16);
            glds16((const char*)(Bt + (size_t)(col0 + r) * KSTRIDE + k0) + ((gS ^ (r & 7)) << 4),
                   Bs + w * 4096 + i * 1024 + lane * 16);
        }
    };

    stage(0, 0);
    __syncthreads();
    for (int kt = 0; kt < KT; ++kt) {
        if (kt + 1 < KT) stage((kt + 1) & 1, kt + 1);
        const char* As = smem + (kt & 1) * 32768;
        const char* Bs = As + 16384;
        const int rA = (w >> 1) * 64 + lo;
        const int rB = (w & 1) * 64 + lo;
#pragma unroll
        for (int s = 0; s < 4; ++s) {
            const int g = s * 2 + hi;
            bf16x8 fa0 = *(const bf16x8*)(As + rA * 128 + ((g ^ (rA & 7)) << 4));
            bf16x8 fa1 = *(const bf16x8*)(As + (rA + 32) * 128 + ((g ^ (rA & 7)) << 4));
            bf16x8 fb0 = *(const bf16x8*)(Bs + rB * 128 + ((g ^ (rB & 7)) << 4));
            bf16x8 fb1 = *(const bf16x8*)(Bs + (rB + 32) * 128 + ((g ^ (rB & 7)) << 4));
            acc[0][0] = __builtin_amdgcn_mfma_f32_32x32x16_bf16(fa0, fb0, acc[0][0], 0, 0, 0);
            acc[0][1] = __builtin_amdgcn_mfma_f32_32x32x16_bf16(fa0, fb1, acc[0][1], 0, 0, 0);
            acc[1][0] = __builtin_amdgcn_mfma_f32_32x32x16_bf16(fa1, fb0, acc[1][0], 0, 0, 0);
            acc[1][1] = __builtin_amdgcn_mfma_f32_32x32x16_bf16(fa1, fb1, acc[1][1], 0, 0, 0);
        }
        __syncthreads();
    }
#pragma unroll
    for (int m = 0; m < 2; ++m)
#pragma unroll
    for (int n = 0; n < 2; ++n) {
        const int c0 = col0 + (w & 1) * 64 + n * 32;
        const float bv = (z == 0) ? bias[c0 + lo] : 0.f;
#pragma unroll
        for (int r = 0; r < 16; ++r) {
            const int gr = row0 + (w >> 1) * 64 + m * 32 + (r & 3) + 8 * (r >> 2) + 4 * hi;
            float vv = acc[m][n][r] + bv;
            if (RELU) vv = fmaxf(vv, 0.f);
            if (OUTF) outf[(size_t)z * 8192 * NFULL + (size_t)gr * NFULL + c0 + lo] = vv;
            if (OUTB) outb[(size_t)gr * NFULL + c0 + lo] = bfu(vv);
        }
    }
}

// ---------------- fused partial-sum + residual + LayerNorm ----------------
template<int DUAL>
__global__ __launch_bounds__(256) void k_lnsum(
    const float* __restrict__ pa, const float* __restrict__ pb,
    const float* __restrict__ res, const float* __restrict__ g,
    const float* __restrict__ bt, float* __restrict__ outf,
    unsigned short* __restrict__ outb)
{
    const int row = blockIdx.x * 4 + (threadIdx.x >> 6);
    const int lane = threadIdx.x & 63;
    const size_t base = (size_t)row * 256;
    float4 v  = ((const float4*)(pa + base))[lane];
    float4 v2 = ((const float4*)(pb + base))[lane];
    float4 v3 = ((const float4*)(res + base))[lane];
    v.x += v2.x + v3.x; v.y += v2.y + v3.y; v.z += v2.z + v3.z; v.w += v2.w + v3.w;
    float s  = v.x + v.y + v.z + v.w;
    float ss = v.x * v.x + v.y * v.y + v.z * v.z + v.w * v.w;
#pragma unroll
    for (int off = 32; off; off >>= 1) { s += __shfl_xor(s, off); ss += __shfl_xor(ss, off); }
    const float mu = s * (1.f / 256.f);
    const float rstd = rsqrtf(ss * (1.f / 256.f) - mu * mu + LNEPS);
    const float4 gg = ((const float4*)g)[lane];
    const float4 bb = ((const float4*)bt)[lane];
    float4 o;
    o.x = (v.x - mu) * rstd * gg.x + bb.x;
    o.y = (v.y - mu) * rstd * gg.y + bb.y;
    o.z = (v.z - mu) * rstd * gg.z + bb.z;
    o.w = (v.w - mu) * rstd * gg.w + bb.w;
    ((float4*)(outf + base))[lane] = o;
    if (DUAL) {
        ushort4 ob; ob.x = bfu(o.x); ob.y = bfu(o.y); ob.z = bfu(o.z); ob.w = bfu(o.w);
        ((ushort4*)(outb + base))[lane] = ob;
    }
}

extern "C" void kernel_launch(void* const* d_in, const int* in_sizes, int n_in,
                              void* d_out, int out_size, void* d_ws, size_t ws_size,
                              hipStream_t stream) {
    const float* x   = (const float*)d_in[0];
    const float* wq  = (const float*)d_in[1];  const float* bq  = (const float*)d_in[2];
    const float* wk  = (const float*)d_in[3];  const float* bk  = (const float*)d_in[4];
    const float* wv  = (const float*)d_in[5];  const float* bv  = (const float*)d_in[6];
    const float* wo  = (const float*)d_in[7];  const float* wob = (const float*)d_in[8];
    const float* w1  = (const float*)d_in[9];  const float* b1  = (const float*)d_in[10];
    const float* w2  = (const float*)d_in[11]; const float* b2  = (const float*)d_in[12];
    const float* g1  = (const float*)d_in[13]; const float* bl1 = (const float*)d_in[14];
    const float* g2  = (const float*)d_in[15]; const float* bl2 = (const float*)d_in[16];

    char* ws = (char*)d_ws;
    unsigned short* xb    = (unsigned short*)(ws + B_XB);
    unsigned short* qb    = (unsigned short*)(ws + B_QB);
    unsigned short* kbuf  = (unsigned short*)(ws + B_KB);
    unsigned short* vt    = (unsigned short*)(ws + B_VT);
    unsigned short* ctxb  = (unsigned short*)(ws + B_CTX);
    unsigned short* o1b   = (unsigned short*)(ws + B_O1B);
    float*          o1f   = (float*)(ws + B_O1F);
    unsigned short* mid   = (unsigned short*)(ws + B_MID);
    float*          c1    = (float*)(ws + B_MID);    // partials, dead before mid written
    float*          c2    = (float*)(ws + B_C2);     // partials, alias xb/qb/kb/vt (dead)
    unsigned short* wqkvT = (unsigned short*)(ws + B_WQKVT);
    unsigned short* woT   = (unsigned short*)(ws + B_WOT);
    unsigned short* w1T   = (unsigned short*)(ws + B_W1T);
    unsigned short* w2T   = (unsigned short*)(ws + B_W2T);
    float* bqkv = (float*)(ws + B_BQKV);
    unsigned int* hqp = (unsigned int*)(ws + B_HQ);
    unsigned int* hkp = (unsigned int*)(ws + B_HK);
    float* out  = (float*)d_out;

    k_packall<<<dim3(2819), dim3(256), 0, stream>>>(wq, wk, wv, wo, w1, w2, bq, bk, bv, x,
                                                    wqkvT, woT, w1T, w2T, bqkv, xb);
    k_qkv<<<dim3(64, 6), dim3(256), 0, stream>>>(xb, wqkvT, bqkv, qb, kbuf, vt);
    k_h2<<<dim3(256), dim3(256), 0, stream>>>(qb, kbuf, hqp, hkp);
    k_attn<<<dim3(1024), dim3(512), 0, stream>>>(qb, kbuf, vt, hqp, hkp, ctxb);
    k_gemm<256, 2, 256, 0, 1, 0><<<dim3(64, 2, 2), dim3(256), 0, stream>>>(ctxb, woT, wob, c1, nullptr);
    k_lnsum<1><<<dim3(2048), dim3(256), 0, stream>>>(c1, c1 + 2097152, x, g1, bl1, o1f, o1b);
    k_gemm<256, 4, 1024, 1, 0, 1><<<dim3(64, 8, 1), dim3(256), 0, stream>>>(o1b, w1T, b1, nullptr, mid);
    k_gemm<1024, 8, 256, 0, 1, 0><<<dim3(64, 2, 2), dim3(256), 0, stream>>>(mid, w2T, b2, c2, nullptr);
    k_lnsum<0><<<dim3(2048), dim3(256), 0, stream>>>(c2, c2 + 2097152, o1f, g2, bl2, out, nullptr);
}

// Round 7
// 192.027 us; speedup vs baseline: 2.0480x; 2.0480x over previous
//
#include <hip/hip_runtime.h>
#include <hip/hip_bf16.h>

#define SQL  2048
#define DM   256
#define LNEPS 1e-6f
#define LOG2E    (1.44269504f)

// ---- workspace layout (byte offsets) ----
#define B_XB    (0ull)            // 4 MB  x bf16 [8192][256]
#define B_QB    (4ull<<20)        // 4 MB  q bf16 [bh][s][32]  (pre-scaled by log2e)
#define B_KB    (8ull<<20)        // 4 MB  k bf16 [bh][s][32]
#define B_VT    (12ull<<20)       // 4 MB  V^T bf16 [bh][32][2048], pre-swizzled
#define B_CTX   (16ull<<20)       // 4 MB  ctx bf16 [8192][256]
#define B_O1B   (20ull<<20)       // 4 MB  out1 bf16
#define B_O1F   (24ull<<20)       // 8 MB  out1 f32
#define B_MID   (32ull<<20)       // 16 MB mid bf16 [8192][1024]; ALSO c1 partials (2x8MB)
#define B_WQKVT (48ull<<20)       // 384 KB bf16 [768][256]
#define B_WOT   ((48ull<<20)+(512ull<<10))  // 128 KB
#define B_W1T   (49ull<<20)       // 512 KB bf16 [1024][256]
#define B_W2T   ((49ull<<20)+(512ull<<10))  // 512 KB bf16 [256][1024]
#define B_BQKV  (50ull<<20)       // 3 KB f32
#define B_HQ    ((50ull<<20)+(64ull<<10))   // 256 KB u32 packed {1.0,hq}
#define B_HK    ((50ull<<20)+(320ull<<10))  // 256 KB u32 packed {hk,1.0}
#define B_C2    (0ull)            // 16 MB f32 partials (alias xb/qb/kb/vt, dead)

typedef float  f32x16 __attribute__((ext_vector_type(16)));
typedef short  bf16x8 __attribute__((ext_vector_type(8)));
typedef int    i32x4  __attribute__((ext_vector_type(4)));
typedef int    i32x2  __attribute__((ext_vector_type(2)));

static __device__ __forceinline__ unsigned short bfu(float f){
    __hip_bfloat16 h = __float2bfloat16(f);
    return *reinterpret_cast<unsigned short*>(&h);
}
static __device__ __forceinline__ unsigned pk2(float a, float b){
    return (unsigned)bfu(a) | ((unsigned)bfu(b) << 16);
}
static __device__ __forceinline__ void glds16(const void* g, void* l){
    __builtin_amdgcn_global_load_lds((const __attribute__((address_space(1))) unsigned int*)g,
                                     (__attribute__((address_space(3))) unsigned int*)l, 16, 0, 0);
}

// ---------------- fused packing: weights->bf16^T, biases, x->bf16 ----------------
__global__ __launch_bounds__(256) void k_packall(
    const float* __restrict__ wq, const float* __restrict__ wk, const float* __restrict__ wv,
    const float* __restrict__ wo, const float* __restrict__ w1, const float* __restrict__ w2,
    const float* __restrict__ bq, const float* __restrict__ bk, const float* __restrict__ bv,
    const float* __restrict__ x,
    unsigned short* __restrict__ wqkvT, unsigned short* __restrict__ woT,
    unsigned short* __restrict__ w1T, unsigned short* __restrict__ w2T,
    float* __restrict__ bqkv, unsigned short* __restrict__ xb)
{
    __shared__ float tile[32][33];
    const int bid = blockIdx.x;
    const int t = threadIdx.x;
    if (bid < 768) {
        const float* W; unsigned short* Wt; int K, N, xk, yn;
        if (bid < 192) {
            int which = bid >> 6, local = bid & 63;
            W = (which == 0) ? wq : (which == 1 ? wk : wv);
            Wt = wqkvT + which * 65536; K = 256; N = 256;
            xk = local & 7; yn = local >> 3;
        } else if (bid < 256) {
            int local = bid - 192; W = wo; Wt = woT; K = 256; N = 256;
            xk = local & 7; yn = local >> 3;
        } else if (bid < 512) {
            int local = bid - 256; W = w1; Wt = w1T; K = 256; N = 1024;
            xk = local & 7; yn = local >> 3;
        } else {
            int local = bid - 512; W = w2; Wt = w2T; K = 1024; N = 256;
            xk = local & 31; yn = local >> 5;
        }
        const int tx = t & 31, ty = t >> 5;
        const int kb = xk * 32, nb = yn * 32;
#pragma unroll
        for (int i = 0; i < 32; i += 8) tile[ty + i][tx] = W[(size_t)(kb + ty + i) * N + nb + tx];
        __syncthreads();
#pragma unroll
        for (int i = 0; i < 32; i += 8) Wt[(size_t)(nb + ty + i) * K + kb + tx] = bfu(tile[tx][ty + i]);
    } else if (bid < 771) {
        int wb = bid - 768;
        const float* s = (wb == 0) ? bq : (wb == 1 ? bk : bv);
        bqkv[wb * 256 + t] = s[t];
    } else {
        const int i = (bid - 771) * 256 + t;
        float4 v = ((const float4*)x)[i];
        ushort4 o; o.x = bfu(v.x); o.y = bfu(v.y); o.z = bfu(v.z); o.w = bfu(v.w);
        ((ushort4*)xb)[i] = o;
    }
}

// ---------------- QKV GEMM (2-phase dbuf): q scaled by log2e; v -> VT pre-swizzled ----------------
__global__ __launch_bounds__(256, 2) void k_qkv(
    const unsigned short* __restrict__ A, const unsigned short* __restrict__ Bt,
    const float* __restrict__ bias,
    unsigned short* __restrict__ qb, unsigned short* __restrict__ kb,
    char* __restrict__ vtg)
{
    __shared__ __align__(16) char smem[65536];
    const int t = threadIdx.x;
    const int lane = t & 63, w = t >> 6;
    const int lo = lane & 31, hi = lane >> 5;
    const int row0 = blockIdx.x * 128;
    const int col0 = blockIdx.y * 128;
    f32x16 acc[2][2] = {};
    const int gS = lane & 7;
    const int rr = w * 32 + (lane >> 3);

    auto stage = [&](int buf, int kt) {
        const int k0 = kt * 64;
        char* As = smem + buf * 32768;
        char* Bs = As + 16384;
#pragma unroll
        for (int i = 0; i < 4; ++i) {
            const int r = rr + i * 8;
            glds16((const char*)(A  + (size_t)(row0 + r) * 256 + k0) + ((gS ^ (r & 7)) << 4),
                   As + w * 4096 + i * 1024 + lane * 16);
            glds16((const char*)(Bt + (size_t)(col0 + r) * 256 + k0) + ((gS ^ (r & 7)) << 4),
                   Bs + w * 4096 + i * 1024 + lane * 16);
        }
    };

    stage(0, 0);
    __syncthreads();
    for (int kt = 0; kt < 4; ++kt) {
        if (kt + 1 < 4) stage((kt + 1) & 1, kt + 1);
        const char* As = smem + (kt & 1) * 32768;
        const char* Bs = As + 16384;
        const int rA = (w >> 1) * 64 + lo;
        const int rB = (w & 1) * 64 + lo;
#pragma unroll
        for (int s = 0; s < 4; ++s) {
            const int g = s * 2 + hi;
            bf16x8 fa0 = *(const bf16x8*)(As + rA * 128 + ((g ^ (rA & 7)) << 4));
            bf16x8 fa1 = *(const bf16x8*)(As + (rA + 32) * 128 + ((g ^ (rA & 7)) << 4));
            bf16x8 fb0 = *(const bf16x8*)(Bs + rB * 128 + ((g ^ (rB & 7)) << 4));
            bf16x8 fb1 = *(const bf16x8*)(Bs + (rB + 32) * 128 + ((g ^ (rB & 7)) << 4));
            acc[0][0] = __builtin_amdgcn_mfma_f32_32x32x16_bf16(fa0, fb0, acc[0][0], 0, 0, 0);
            acc[0][1] = __builtin_amdgcn_mfma_f32_32x32x16_bf16(fa0, fb1, acc[0][1], 0, 0, 0);
            acc[1][0] = __builtin_amdgcn_mfma_f32_32x32x16_bf16(fa1, fb0, acc[1][0], 0, 0, 0);
            acc[1][1] = __builtin_amdgcn_mfma_f32_32x32x16_bf16(fa1, fb1, acc[1][1], 0, 0, 0);
        }
        __syncthreads();
    }
#pragma unroll
    for (int m = 0; m < 2; ++m)
#pragma unroll
    for (int n = 0; n < 2; ++n) {
        const int c0 = col0 + (w & 1) * 64 + n * 32;
        const int which = c0 >> 8, h = (c0 >> 5) & 7;
        const float bv = bias[c0 + lo];
        if (which < 2) {
            unsigned short* dst = (which == 0) ? qb : kb;
            const float scl = (which == 0) ? LOG2E : 1.0f;
#pragma unroll
            for (int r = 0; r < 16; ++r) {
                const int gr = row0 + (w >> 1) * 64 + m * 32 + (r & 3) + 8 * (r >> 2) + 4 * hi;
                const int b = gr >> 11, s = gr & 2047;
                dst[(((size_t)(b * 8 + h)) * SQL + s) * 32 + lo] = bfu((acc[m][n][r] + bv) * scl);
            }
        } else {
            // V -> VT[bh][d=lo][s], 8B-unit swizzle within each 128B block
#pragma unroll
            for (int r = 0; r < 16; ++r) {
                const int gr = row0 + (w >> 1) * 64 + m * 32 + (r & 3) + 8 * (r >> 2) + 4 * hi;
                const int b = gr >> 11, s = gr & 2047;
                const int o = s * 2;
                const int op = (o & ~0x78) | ((((o >> 3) & 15) ^ (lo & 15)) << 3);
                *(unsigned short*)(vtg + ((size_t)(b * 8 + h)) * 131072 + (size_t)lo * 4096 + op)
                    = bfu(acc[m][n][r] + bv);
            }
        }
    }
}

// ---------------- hq/hk packed as ready MFMA fragment words ----------------
__global__ __launch_bounds__(256) void k_h2(const unsigned short* __restrict__ qb,
                                            const unsigned short* __restrict__ kb,
                                            unsigned int* __restrict__ hqp,
                                            unsigned int* __restrict__ hkp)
{
    const int gid = blockIdx.x * 256 + threadIdx.x;
    const unsigned short* qp = qb + (size_t)gid * 32;
    const unsigned short* kp = kb + (size_t)gid * 32;
    float sq = 0.f, sk = 0.f;
#pragma unroll
    for (int i = 0; i < 4; ++i) {
        i32x4 qv = *(const i32x4*)(qp + i * 8);
        i32x4 kv = *(const i32x4*)(kp + i * 8);
#pragma unroll
        for (int j = 0; j < 4; ++j) {
            unsigned int qw = (unsigned int)qv[j], kw = (unsigned int)kv[j];
            float a = __builtin_bit_cast(float, qw << 16);
            float c = __builtin_bit_cast(float, qw & 0xffff0000u);
            float d = __builtin_bit_cast(float, kw << 16);
            float e = __builtin_bit_cast(float, kw & 0xffff0000u);
            sq += a * a + c * c; sk += d * d + e * e;
        }
    }
    const float hq = -0.34657359f * sq + 0.52876637f;
    const float hk = -0.72134752f * sk;
    hqp[gid] = 0x3F80u | ((unsigned)bfu(hq) << 16);        // B3: {k0:1.0, k1:hq}
    hkp[gid] = (unsigned)bfu(hk) | 0x3F800000u;            // A3: {k0:hk,  k1:1.0}
}

// ---------------- MFMA attention: 4 key-groups x 2 q-waves, LDS unioned, setprio, XCD swizzle ----------------
__global__ __launch_bounds__(512, 4) void k_attn(
    const unsigned short* __restrict__ qg, const unsigned short* __restrict__ kg,
    const char* __restrict__ vtg, const unsigned int* __restrict__ hqp,
    const unsigned int* __restrict__ hkp, unsigned short* __restrict__ ctxb)
{
    // [0,16384) kls | [16384,32768) vtl | [32768,33792) hks | [33792,34048) invs
    // epilogue union: redacc [0,24576) | redden [24576,26112)
    __shared__ __align__(16) char smem[34048];
    char* kls = smem;
    char* vtl = smem + 16384;
    float* hks  = (float*)(smem + 32768);
    float* invs = (float*)(smem + 33792);
    float* redacc = (float*)smem;
    float* redden = (float*)(smem + 24576);

    const int t = threadIdx.x;
    const int grp = t >> 7;          // 0..3 key-group
    const int tl  = t & 127;
    const int lane = t & 63;
    const int w   = (t >> 6) & 1;    // q sub-block wave
    const int lo = lane & 31;
    const int hi = lane >> 5;

    // XCD-aware bijective swizzle (1024 % 8 == 0): same-bh blocks share an XCD L2
    const int bid = (blockIdx.x & 7) * 128 + (blockIdx.x >> 3);
    const int qc = bid & 31;
    const int bh = bid >> 5;

    const int qrow = qc * 64 + w * 32 + lo;
    const unsigned short* qp = qg + ((size_t)bh * SQL + qrow) * 32;
    const bf16x8 qf0 = *(const bf16x8*)(qp + hi * 8);
    const bf16x8 qf1 = *(const bf16x8*)(qp + 16 + hi * 8);
    i32x4 b3i = {};
    if (hi == 0) b3i[0] = (int)hqp[(size_t)bh * SQL + qrow];
    const bf16x8 b3 = __builtin_bit_cast(bf16x8, b3i);

    f32x16 acc = {};
    float den = 0.f;

    const unsigned short* kbg = kg + (size_t)bh * SQL * 32;
    const char* vtb = vtg + (size_t)bh * 131072;
    const unsigned int* hkb = hkp + (size_t)bh * SQL;
    char* kd = kls + grp * 4096;
    char* vd = vtl + grp * 4096;

    for (int kt = 0; kt < 8; ++kt) {
        const int key0 = grp * 512 + kt * 64;
        {
#pragma unroll
            for (int it = 0; it < 2; ++it) {
                const int idx = it * 128 + tl;
                const int r = idx >> 2, gl = idx & 3;
                glds16((const char*)(kbg + (size_t)(key0 + r) * 32) + ((gl ^ ((r >> 1) & 3)) << 4),
                       kd + idx * 16);
                const int vrw = idx >> 3, vch = idx & 7;
                glds16(vtb + (size_t)vrw * 4096 + key0 * 2 + vch * 16, vd + idx * 16);
            }
            if (tl < 64) hks[grp * 64 + tl] = __builtin_bit_cast(float, hkb[key0 + tl]);
        }
        __syncthreads();

#pragma unroll
        for (int h2 = 0; h2 < 2; ++h2) {
            const int kb32 = h2 * 32;
            const int kA = kb32 + lo;
            const char* krow = kd + kA * 64;
            const int ksw = (kA >> 1) & 3;
            bf16x8 kf0 = *(const bf16x8*)(krow + (((0 + hi) ^ ksw) << 4));
            bf16x8 kf1 = *(const bf16x8*)(krow + (((2 + hi) ^ ksw) << 4));
            i32x4 a3i = {};
            if (hi == 0) a3i[0] = __builtin_bit_cast(int, hks[grp * 64 + kA]);
            f32x16 sc = {};
            __builtin_amdgcn_s_setprio(1);
            sc = __builtin_amdgcn_mfma_f32_32x32x16_bf16(kf0, qf0, sc, 0, 0, 0);
            sc = __builtin_amdgcn_mfma_f32_32x32x16_bf16(kf1, qf1, sc, 0, 0, 0);
            sc = __builtin_amdgcn_mfma_f32_32x32x16_bf16(
                     __builtin_bit_cast(bf16x8, a3i), b3, sc, 0, 0, 0);
            __builtin_amdgcn_s_setprio(0);
            float wv[16];
#pragma unroll
            for (int r = 0; r < 16; ++r) {
                float e1 = __builtin_amdgcn_exp2f(sc[r]);   // = log2e * exp(-0.5 d)
                float ww = __builtin_amdgcn_exp2f(e1);      // = e^{exp(-0.5 d)}
                den += ww;
                wv[r] = ww;
            }
            i32x4 p0; p0[0]=pk2(wv[0],wv[1]);   p0[1]=pk2(wv[2],wv[3]);
                      p0[2]=pk2(wv[4],wv[5]);   p0[3]=pk2(wv[6],wv[7]);
            i32x4 p1; p1[0]=pk2(wv[8],wv[9]);   p1[1]=pk2(wv[10],wv[11]);
                      p1[2]=pk2(wv[12],wv[13]); p1[3]=pk2(wv[14],wv[15]);
            const char* vrow = vd + lo * 128;
            const int vxor = (lo & 15) << 3;
            const int o0 = (kb32 + 4 * hi) * 2;
            const int o1 = (kb32 + 16 + 4 * hi) * 2;
            i32x2 a0 = *(const i32x2*)(vrow + (o0 ^ vxor));
            i32x2 a1 = *(const i32x2*)(vrow + ((o0 + 16) ^ vxor));
            i32x2 b0 = *(const i32x2*)(vrow + (o1 ^ vxor));
            i32x2 b1 = *(const i32x2*)(vrow + ((o1 + 16) ^ vxor));
            i32x4 vb0; vb0[0]=a0[0]; vb0[1]=a0[1]; vb0[2]=a1[0]; vb0[3]=a1[1];
            i32x4 vb1; vb1[0]=b0[0]; vb1[1]=b0[1]; vb1[2]=b1[0]; vb1[3]=b1[1];
            __builtin_amdgcn_s_setprio(1);
            acc = __builtin_amdgcn_mfma_f32_32x32x16_bf16(
                __builtin_bit_cast(bf16x8, p0), __builtin_bit_cast(bf16x8, vb0), acc, 0, 0, 0);
            acc = __builtin_amdgcn_mfma_f32_32x32x16_bf16(
                __builtin_bit_cast(bf16x8, p1), __builtin_bit_cast(bf16x8, vb1), acc, 0, 0, 0);
            __builtin_amdgcn_s_setprio(0);
        }
        __syncthreads();
    }

    // ---- cross-group tree reduction (redacc unioned over kls/vtl; main loop done) ----
    if (grp != 0) {
#pragma unroll
        for (int r = 0; r < 16; ++r) redacc[((grp - 1) * 16 + r) * 128 + tl] = acc[r];
        redden[(grp - 1) * 128 + tl] = den;
    }
    __syncthreads();
    if (grp == 0) {
#pragma unroll
        for (int r = 0; r < 16; ++r)
            acc[r] += redacc[r * 128 + tl] + redacc[(16 + r) * 128 + tl] + redacc[(32 + r) * 128 + tl];
        den += redden[tl] + redden[128 + tl] + redden[256 + tl];
        const float dfull = den + __shfl_xor(den, 32);
        if (hi == 0) invs[w * 32 + lo] = 1.f / dfull;
        // same-wave LDS write->read, no barrier needed
        float4 i0 = *(const float4*)&invs[w * 32 + 4 * hi];
        float4 i1 = *(const float4*)&invs[w * 32 + 8 + 4 * hi];
        float4 i2 = *(const float4*)&invs[w * 32 + 16 + 4 * hi];
        float4 i3 = *(const float4*)&invs[w * 32 + 24 + 4 * hi];
        float iv[16] = {i0.x,i0.y,i0.z,i0.w, i1.x,i1.y,i1.z,i1.w,
                        i2.x,i2.y,i2.z,i2.w, i3.x,i3.y,i3.z,i3.w};
        const int b = bh >> 3, h = bh & 7;
        unsigned short* cbase = ctxb + ((size_t)(b * SQL + qc * 64 + w * 32)) * 256 + h * 32 + lo;
#pragma unroll
        for (int r = 0; r < 16; ++r) {
            const int qr = (r & 3) + 8 * (r >> 2) + 4 * hi;
            cbase[(size_t)qr * 256] = bfu(acc[r] * iv[r]);
        }
    }
}

// ---------------- generic MFMA GEMM, 2-phase dbuf, split-K via blockIdx.z ----------------
template<int KSTRIDE, int KT, int NFULL, int RELU, int OUTF, int OUTB>
__global__ __launch_bounds__(256, 2) void k_gemm(
    const unsigned short* __restrict__ A, const unsigned short* __restrict__ Bt,
    const float* __restrict__ bias,
    float* __restrict__ outf, unsigned short* __restrict__ outb)
{
    __shared__ __align__(16) char smem[65536];
    const int t = threadIdx.x;
    const int lane = t & 63, w = t >> 6;
    const int lo = lane & 31, hi = lane >> 5;
    const int row0 = blockIdx.x * 128;
    const int col0 = blockIdx.y * 128;
    const int z = blockIdx.z;
    f32x16 acc[2][2] = {};
    const int gS = lane & 7;
    const int rr = w * 32 + (lane >> 3);

    auto stage = [&](int buf, int kt) {
        const int k0 = (z * KT + kt) * 64;
        char* As = smem + buf * 32768;
        char* Bs = As + 16384;
#pragma unroll
        for (int i = 0; i < 4; ++i) {
            const int r = rr + i * 8;
            glds16((const char*)(A  + (size_t)(row0 + r) * KSTRIDE + k0) + ((gS ^ (r & 7)) << 4),
                   As + w * 4096 + i * 1024 + lane * 16);
            glds16((const char*)(Bt + (size_t)(col0 + r) * KSTRIDE + k0) + ((gS ^ (r & 7)) << 4),
                   Bs + w * 4096 + i * 1024 + lane * 16);
        }
    };

    stage(0, 0);
    __syncthreads();
    for (int kt = 0; kt < KT; ++kt) {
        if (kt + 1 < KT) stage((kt + 1) & 1, kt + 1);
        const char* As = smem + (kt & 1) * 32768;
        const char* Bs = As + 16384;
        const int rA = (w >> 1) * 64 + lo;
        const int rB = (w & 1) * 64 + lo;
#pragma unroll
        for (int s = 0; s < 4; ++s) {
            const int g = s * 2 + hi;
            bf16x8 fa0 = *(const bf16x8*)(As + rA * 128 + ((g ^ (rA & 7)) << 4));
            bf16x8 fa1 = *(const bf16x8*)(As + (rA + 32) * 128 + ((g ^ (rA & 7)) << 4));
            bf16x8 fb0 = *(const bf16x8*)(Bs + rB * 128 + ((g ^ (rB & 7)) << 4));
            bf16x8 fb1 = *(const bf16x8*)(Bs + (rB + 32) * 128 + ((g ^ (rB & 7)) << 4));
            acc[0][0] = __builtin_amdgcn_mfma_f32_32x32x16_bf16(fa0, fb0, acc[0][0], 0, 0, 0);
            acc[0][1] = __builtin_amdgcn_mfma_f32_32x32x16_bf16(fa0, fb1, acc[0][1], 0, 0, 0);
            acc[1][0] = __builtin_amdgcn_mfma_f32_32x32x16_bf16(fa1, fb0, acc[1][0], 0, 0, 0);
            acc[1][1] = __builtin_amdgcn_mfma_f32_32x32x16_bf16(fa1, fb1, acc[1][1], 0, 0, 0);
        }
        __syncthreads();
    }
#pragma unroll
    for (int m = 0; m < 2; ++m)
#pragma unroll
    for (int n = 0; n < 2; ++n) {
        const int c0 = col0 + (w & 1) * 64 + n * 32;
        const float bv = (z == 0) ? bias[c0 + lo] : 0.f;
#pragma unroll
        for (int r = 0; r < 16; ++r) {
            const int gr = row0 + (w >> 1) * 64 + m * 32 + (r & 3) + 8 * (r >> 2) + 4 * hi;
            float vv = acc[m][n][r] + bv;
            if (RELU) vv = fmaxf(vv, 0.f);
            if (OUTF) outf[(size_t)z * 8192 * NFULL + (size_t)gr * NFULL + c0 + lo] = vv;
            if (OUTB) outb[(size_t)gr * NFULL + c0 + lo] = bfu(vv);
        }
    }
}

// ---------------- fused partial-sum + residual + LayerNorm ----------------
template<int DUAL>
__global__ __launch_bounds__(256) void k_lnsum(
    const float* __restrict__ pa, const float* __restrict__ pb,
    const float* __restrict__ res, const float* __restrict__ g,
    const float* __restrict__ bt, float* __restrict__ outf,
    unsigned short* __restrict__ outb)
{
    const int row = blockIdx.x * 4 + (threadIdx.x >> 6);
    const int lane = threadIdx.x & 63;
    const size_t base = (size_t)row * 256;
    float4 v  = ((const float4*)(pa + base))[lane];
    float4 v2 = ((const float4*)(pb + base))[lane];
    float4 v3 = ((const float4*)(res + base))[lane];
    v.x += v2.x + v3.x; v.y += v2.y + v3.y; v.z += v2.z + v3.z; v.w += v2.w + v3.w;
    float s  = v.x + v.y + v.z + v.w;
    float ss = v.x * v.x + v.y * v.y + v.z * v.z + v.w * v.w;
#pragma unroll
    for (int off = 32; off; off >>= 1) { s += __shfl_xor(s, off); ss += __shfl_xor(ss, off); }
    const float mu = s * (1.f / 256.f);
    const float rstd = rsqrtf(ss * (1.f / 256.f) - mu * mu + LNEPS);
    const float4 gg = ((const float4*)g)[lane];
    const float4 bb = ((const float4*)bt)[lane];
    float4 o;
    o.x = (v.x - mu) * rstd * gg.x + bb.x;
    o.y = (v.y - mu) * rstd * gg.y + bb.y;
    o.z = (v.z - mu) * rstd * gg.z + bb.z;
    o.w = (v.w - mu) * rstd * gg.w + bb.w;
    ((float4*)(outf + base))[lane] = o;
    if (DUAL) {
        ushort4 ob; ob.x = bfu(o.x); ob.y = bfu(o.y); ob.z = bfu(o.z); ob.w = bfu(o.w);
        ((ushort4*)(outb + base))[lane] = ob;
    }
}

extern "C" void kernel_launch(void* const* d_in, const int* in_sizes, int n_in,
                              void* d_out, int out_size, void* d_ws, size_t ws_size,
                              hipStream_t stream) {
    const float* x   = (const float*)d_in[0];
    const float* wq  = (const float*)d_in[1];  const float* bq  = (const float*)d_in[2];
    const float* wk  = (const float*)d_in[3];  const float* bk  = (const float*)d_in[4];
    const float* wv  = (const float*)d_in[5];  const float* bv  = (const float*)d_in[6];
    const float* wo  = (const float*)d_in[7];  const float* wob = (const float*)d_in[8];
    const float* w1  = (const float*)d_in[9];  const float* b1  = (const float*)d_in[10];
    const float* w2  = (const float*)d_in[11]; const float* b2  = (const float*)d_in[12];
    const float* g1  = (const float*)d_in[13]; const float* bl1 = (const float*)d_in[14];
    const float* g2  = (const float*)d_in[15]; const float* bl2 = (const float*)d_in[16];

    char* ws = (char*)d_ws;
    unsigned short* xb    = (unsigned short*)(ws + B_XB);
    unsigned short* qb    = (unsigned short*)(ws + B_QB);
    unsigned short* kbuf  = (unsigned short*)(ws + B_KB);
    char*           vt    = (char*)(ws + B_VT);
    unsigned short* ctxb  = (unsigned short*)(ws + B_CTX);
    unsigned short* o1b   = (unsigned short*)(ws + B_O1B);
    float*          o1f   = (float*)(ws + B_O1F);
    unsigned short* mid   = (unsigned short*)(ws + B_MID);
    float*          c1    = (float*)(ws + B_MID);    // partials, dead before mid written
    float*          c2    = (float*)(ws + B_C2);     // partials, alias xb/qb/kb/vt (dead)
    unsigned short* wqkvT = (unsigned short*)(ws + B_WQKVT);
    unsigned short* woT   = (unsigned short*)(ws + B_WOT);
    unsigned short* w1T   = (unsigned short*)(ws + B_W1T);
    unsigned short* w2T   = (unsigned short*)(ws + B_W2T);
    float* bqkv = (float*)(ws + B_BQKV);
    unsigned int* hqp = (unsigned int*)(ws + B_HQ);
    unsigned int* hkp = (unsigned int*)(ws + B_HK);
    float* out  = (float*)d_out;

    k_packall<<<dim3(2819), dim3(256), 0, stream>>>(wq, wk, wv, wo, w1, w2, bq, bk, bv, x,
                                                    wqkvT, woT, w1T, w2T, bqkv, xb);
    k_qkv<<<dim3(64, 6), dim3(256), 0, stream>>>(xb, wqkvT, bqkv, qb, kbuf, vt);
    k_h2<<<dim3(256), dim3(256), 0, stream>>>(qb, kbuf, hqp, hkp);
    k_attn<<<dim3(1024), dim3(512), 0, stream>>>(qb, kbuf, vt, hqp, hkp, ctxb);
    k_gemm<256, 2, 256, 0, 1, 0><<<dim3(64, 2, 2), dim3(256), 0, stream>>>(ctxb, woT, wob, c1, nullptr);
    k_lnsum<1><<<dim3(2048), dim3(256), 0, stream>>>(c1, c1 + 2097152, x, g1, bl1, o1f, o1b);
    k_gemm<256, 4, 1024, 1, 0, 1><<<dim3(64, 8, 1), dim3(256), 0, stream>>>(o1b, w1T, b1, nullptr, mid);
    k_gemm<1024, 8, 256, 0, 1, 0><<<dim3(64, 2, 2), dim3(256), 0, stream>>>(mid, w2T, b2, c2, nullptr);
    k_lnsum<0><<<dim3(2048), dim3(256), 0, stream>>>(c2, c2 + 2097152, o1f, g2, bl2, out, nullptr);
}

// Round 9
// 191.119 us; speedup vs baseline: 2.0577x; 1.0047x over previous
//
#include <hip/hip_runtime.h>
#include <hip/hip_bf16.h>

#define SQL  2048
#define DM   256
#define LNEPS 1e-6f
#define LOG2E    (1.44269504f)

// ---- workspace layout (byte offsets) ----
#define B_XB    (0ull)            // 4 MB  x bf16 [8192][256]
#define B_QB    (4ull<<20)        // 4 MB  q bf16 [bh][s][32]  (pre-scaled by log2e)
#define B_KB    (8ull<<20)        // 4 MB  k bf16 [bh][s][32]
#define B_VT    (12ull<<20)       // 4 MB  V^T bf16 [bh][32][2048], pre-swizzled
#define B_CTX   (16ull<<20)       // 4 MB  ctx bf16 [8192][256]
#define B_O1B   (20ull<<20)       // 4 MB  out1 bf16
#define B_O1F   (24ull<<20)       // 8 MB  out1 f32
#define B_MID   (32ull<<20)       // 16 MB mid bf16 [8192][1024]; c1 f32 (8MB) aliases (dead first)
#define B_WQKVT (48ull<<20)       // 384 KB bf16 [768][256]
#define B_WOT   ((48ull<<20)+(512ull<<10))  // 128 KB
#define B_W1T   (49ull<<20)       // 512 KB bf16 [1024][256]
#define B_W2T   ((49ull<<20)+(512ull<<10))  // 512 KB bf16 [256][1024]
#define B_BQKV  (50ull<<20)       // 3 KB f32
#define B_HQ    ((50ull<<20)+(64ull<<10))   // 256 KB u32 packed {1.0,hq}
#define B_HK    ((50ull<<20)+(320ull<<10))  // 256 KB u32 packed {hk,1.0}
#define B_C2    (0ull)            // 8 MB f32 (alias xb/qb, dead by then)

typedef float  f32x16 __attribute__((ext_vector_type(16)));
typedef short  bf16x8 __attribute__((ext_vector_type(8)));
typedef int    i32x4  __attribute__((ext_vector_type(4)));
typedef int    i32x2  __attribute__((ext_vector_type(2)));

static __device__ __forceinline__ unsigned short bfu(float f){
    __hip_bfloat16 h = __float2bfloat16(f);
    return *reinterpret_cast<unsigned short*>(&h);
}
static __device__ __forceinline__ unsigned pk2(float a, float b){
    return (unsigned)bfu(a) | ((unsigned)bfu(b) << 16);
}
static __device__ __forceinline__ void glds16(const void* g, void* l){
    __builtin_amdgcn_global_load_lds((const __attribute__((address_space(1))) unsigned int*)g,
                                     (__attribute__((address_space(3))) unsigned int*)l, 16, 0, 0);
}

// ---------------- fused packing: weights->bf16^T, biases, x->bf16 ----------------
__global__ __launch_bounds__(256) void k_packall(
    const float* __restrict__ wq, const float* __restrict__ wk, const float* __restrict__ wv,
    const float* __restrict__ wo, const float* __restrict__ w1, const float* __restrict__ w2,
    const float* __restrict__ bq, const float* __restrict__ bk, const float* __restrict__ bv,
    const float* __restrict__ x,
    unsigned short* __restrict__ wqkvT, unsigned short* __restrict__ woT,
    unsigned short* __restrict__ w1T, unsigned short* __restrict__ w2T,
    float* __restrict__ bqkv, unsigned short* __restrict__ xb)
{
    __shared__ float tile[32][33];
    const int bid = blockIdx.x;
    const int t = threadIdx.x;
    if (bid < 768) {
        const float* W; unsigned short* Wt; int K, N, xk, yn;
        if (bid < 192) {
            int which = bid >> 6, local = bid & 63;
            W = (which == 0) ? wq : (which == 1 ? wk : wv);
            Wt = wqkvT + which * 65536; K = 256; N = 256;
            xk = local & 7; yn = local >> 3;
        } else if (bid < 256) {
            int local = bid - 192; W = wo; Wt = woT; K = 256; N = 256;
            xk = local & 7; yn = local >> 3;
        } else if (bid < 512) {
            int local = bid - 256; W = w1; Wt = w1T; K = 256; N = 1024;
            xk = local & 7; yn = local >> 3;
        } else {
            int local = bid - 512; W = w2; Wt = w2T; K = 1024; N = 256;
            xk = local & 31; yn = local >> 5;
        }
        const int tx = t & 31, ty = t >> 5;
        const int kb = xk * 32, nb = yn * 32;
#pragma unroll
        for (int i = 0; i < 32; i += 8) tile[ty + i][tx] = W[(size_t)(kb + ty + i) * N + nb + tx];
        __syncthreads();
#pragma unroll
        for (int i = 0; i < 32; i += 8) Wt[(size_t)(nb + ty + i) * K + kb + tx] = bfu(tile[tx][ty + i]);
    } else if (bid < 771) {
        int wb = bid - 768;
        const float* s = (wb == 0) ? bq : (wb == 1 ? bk : bv);
        bqkv[wb * 256 + t] = s[t];
    } else {
        const int i = (bid - 771) * 256 + t;
        float4 v = ((const float4*)x)[i];
        ushort4 o; o.x = bfu(v.x); o.y = bfu(v.y); o.z = bfu(v.z); o.w = bfu(v.w);
        ((ushort4*)xb)[i] = o;
    }
}

// ---------------- QKV GEMM (64x128 tile): q scaled by log2e; hq/hk fused; v -> VT swizzled ----------------
__global__ __launch_bounds__(256, 4) void k_qkv(
    const unsigned short* __restrict__ A, const unsigned short* __restrict__ Bt,
    const float* __restrict__ bias,
    unsigned short* __restrict__ qb, unsigned short* __restrict__ kb,
    char* __restrict__ vtg,
    unsigned int* __restrict__ hqp, unsigned int* __restrict__ hkp)
{
    __shared__ __align__(16) char As[8192];
    __shared__ __align__(16) char Bs[16384];
    const int t = threadIdx.x;
    const int lane = t & 63, w = t >> 6;
    const int lo = lane & 31, hi = lane >> 5;
    const int row0 = blockIdx.x * 64;
    const int col0 = blockIdx.y * 128;
    const int mr = (w & 1) * 32, nc = (w >> 1) * 64;
    f32x16 acc[2] = {};

    for (int kt = 0; kt < 4; ++kt) {
        const int k0 = kt * 64;
#pragma unroll
        for (int it = 0; it < 2; ++it) {
            const int idx = it * 256 + t;
            const int r = idx >> 3, g = idx & 7;
            glds16((const char*)(A + (size_t)(row0 + r) * 256 + k0) + ((g ^ (r & 7)) << 4),
                   As + it * 4096 + w * 1024 + lane * 16);
        }
#pragma unroll
        for (int it = 0; it < 4; ++it) {
            const int idx = it * 256 + t;
            const int r = idx >> 3, g = idx & 7;
            glds16((const char*)(Bt + (size_t)(col0 + r) * 256 + k0) + ((g ^ (r & 7)) << 4),
                   Bs + it * 4096 + w * 1024 + lane * 16);
        }
        __syncthreads();
        const int rA = mr + lo;
        const int rB = nc + lo;
#pragma unroll
        for (int s = 0; s < 4; ++s) {
            const int g = s * 2 + hi;
            bf16x8 fa  = *(const bf16x8*)(As + rA * 128 + ((g ^ (rA & 7)) << 4));
            bf16x8 fb0 = *(const bf16x8*)(Bs + rB * 128 + ((g ^ (rB & 7)) << 4));
            bf16x8 fb1 = *(const bf16x8*)(Bs + (rB + 32) * 128 + ((g ^ (rB & 7)) << 4));
            acc[0] = __builtin_amdgcn_mfma_f32_32x32x16_bf16(fa, fb0, acc[0], 0, 0, 0);
            acc[1] = __builtin_amdgcn_mfma_f32_32x32x16_bf16(fa, fb1, acc[1], 0, 0, 0);
        }
        __syncthreads();
    }
#pragma unroll
    for (int n = 0; n < 2; ++n) {
        const int c0 = col0 + nc + n * 32;
        const int which = c0 >> 8, h = (c0 >> 5) & 7;
        const float bv = bias[c0 + lo];
        if (which < 2) {
            unsigned short* dst = (which == 0) ? qb : kb;
            const float scl = (which == 0) ? LOG2E : 1.0f;
#pragma unroll
            for (int r = 0; r < 16; ++r) {
                const int gr = row0 + mr + (r & 3) + 8 * (r >> 2) + 4 * hi;
                const int b = gr >> 11, s = gr & 2047;
                const unsigned short u = bfu((acc[n][r] + bv) * scl);
                dst[(((size_t)(b * 8 + h)) * SQL + s) * 32 + lo] = u;
                // fused ||.||^2 over the head's 32 dims (this acc tile = one head)
                const float vr = __builtin_bit_cast(float, ((unsigned)u) << 16);
                float sv = vr * vr;
                sv += __shfl_xor(sv, 1);  sv += __shfl_xor(sv, 2);
                sv += __shfl_xor(sv, 4);  sv += __shfl_xor(sv, 8);
                sv += __shfl_xor(sv, 16);
                if (lo == 0) {
                    const size_t gi = (size_t)(b * 8 + h) * SQL + s;
                    if (which == 0)
                        hqp[gi] = 0x3F80u | ((unsigned)bfu(-0.34657359f * sv + 0.52876637f) << 16);
                    else
                        hkp[gi] = (unsigned)bfu(-0.72134752f * sv) | 0x3F800000u;
                }
            }
        } else {
            // V -> VT[bh][d=lo][s], 8B-unit swizzle within each 128B block
#pragma unroll
            for (int r = 0; r < 16; ++r) {
                const int gr = row0 + mr + (r & 3) + 8 * (r >> 2) + 4 * hi;
                const int b = gr >> 11, s = gr & 2047;
                const int o = s * 2;
                const int op = (o & ~0x78) | ((((o >> 3) & 15) ^ (lo & 15)) << 3);
                *(unsigned short*)(vtg + ((size_t)(b * 8 + h)) * 131072 + (size_t)lo * 4096 + op)
                    = bfu(acc[n][r] + bv);
            }
        }
    }
}

// ---------------- MFMA attention (round-7 structure, unchanged) ----------------
__global__ __launch_bounds__(512, 4) void k_attn(
    const unsigned short* __restrict__ qg, const unsigned short* __restrict__ kg,
    const char* __restrict__ vtg, const unsigned int* __restrict__ hqp,
    const unsigned int* __restrict__ hkp, unsigned short* __restrict__ ctxb)
{
    __shared__ __align__(16) char smem[34048];
    char* kls = smem;
    char* vtl = smem + 16384;
    float* hks  = (float*)(smem + 32768);
    float* invs = (float*)(smem + 33792);
    float* redacc = (float*)smem;
    float* redden = (float*)(smem + 24576);

    const int t = threadIdx.x;
    const int grp = t >> 7;
    const int tl  = t & 127;
    const int lane = t & 63;
    const int w   = (t >> 6) & 1;
    const int lo = lane & 31;
    const int hi = lane >> 5;

    const int bid = (blockIdx.x & 7) * 128 + (blockIdx.x >> 3);
    const int qc = bid & 31;
    const int bh = bid >> 5;

    const int qrow = qc * 64 + w * 32 + lo;
    const unsigned short* qp = qg + ((size_t)bh * SQL + qrow) * 32;
    const bf16x8 qf0 = *(const bf16x8*)(qp + hi * 8);
    const bf16x8 qf1 = *(const bf16x8*)(qp + 16 + hi * 8);
    i32x4 b3i = {};
    if (hi == 0) b3i[0] = (int)hqp[(size_t)bh * SQL + qrow];
    const bf16x8 b3 = __builtin_bit_cast(bf16x8, b3i);

    f32x16 acc = {};
    float den = 0.f;

    const unsigned short* kbg = kg + (size_t)bh * SQL * 32;
    const char* vtb = vtg + (size_t)bh * 131072;
    const unsigned int* hkb = hkp + (size_t)bh * SQL;
    char* kd = kls + grp * 4096;
    char* vd = vtl + grp * 4096;

    for (int kt = 0; kt < 8; ++kt) {
        const int key0 = grp * 512 + kt * 64;
        {
#pragma unroll
            for (int it = 0; it < 2; ++it) {
                const int idx = it * 128 + tl;
                const int r = idx >> 2, gl = idx & 3;
                glds16((const char*)(kbg + (size_t)(key0 + r) * 32) + ((gl ^ ((r >> 1) & 3)) << 4),
                       kd + idx * 16);
                const int vrw = idx >> 3, vch = idx & 7;
                glds16(vtb + (size_t)vrw * 4096 + key0 * 2 + vch * 16, vd + idx * 16);
            }
            if (tl < 64) hks[grp * 64 + tl] = __builtin_bit_cast(float, hkb[key0 + tl]);
        }
        __syncthreads();

#pragma unroll
        for (int h2 = 0; h2 < 2; ++h2) {
            const int kb32 = h2 * 32;
            const int kA = kb32 + lo;
            const char* krow = kd + kA * 64;
            const int ksw = (kA >> 1) & 3;
            bf16x8 kf0 = *(const bf16x8*)(krow + (((0 + hi) ^ ksw) << 4));
            bf16x8 kf1 = *(const bf16x8*)(krow + (((2 + hi) ^ ksw) << 4));
            i32x4 a3i = {};
            if (hi == 0) a3i[0] = __builtin_bit_cast(int, hks[grp * 64 + kA]);
            f32x16 sc = {};
            __builtin_amdgcn_s_setprio(1);
            sc = __builtin_amdgcn_mfma_f32_32x32x16_bf16(kf0, qf0, sc, 0, 0, 0);
            sc = __builtin_amdgcn_mfma_f32_32x32x16_bf16(kf1, qf1, sc, 0, 0, 0);
            sc = __builtin_amdgcn_mfma_f32_32x32x16_bf16(
                     __builtin_bit_cast(bf16x8, a3i), b3, sc, 0, 0, 0);
            __builtin_amdgcn_s_setprio(0);
            float wv[16];
#pragma unroll
            for (int r = 0; r < 16; ++r) {
                float e1 = __builtin_amdgcn_exp2f(sc[r]);
                float ww = __builtin_amdgcn_exp2f(e1);
                den += ww;
                wv[r] = ww;
            }
            i32x4 p0; p0[0]=pk2(wv[0],wv[1]);   p0[1]=pk2(wv[2],wv[3]);
                      p0[2]=pk2(wv[4],wv[5]);   p0[3]=pk2(wv[6],wv[7]);
            i32x4 p1; p1[0]=pk2(wv[8],wv[9]);   p1[1]=pk2(wv[10],wv[11]);
                      p1[2]=pk2(wv[12],wv[13]); p1[3]=pk2(wv[14],wv[15]);
            const char* vrow = vd + lo * 128;
            const int vxor = (lo & 15) << 3;
            const int o0 = (kb32 + 4 * hi) * 2;
            const int o1 = (kb32 + 16 + 4 * hi) * 2;
            i32x2 a0 = *(const i32x2*)(vrow + (o0 ^ vxor));
            i32x2 a1 = *(const i32x2*)(vrow + ((o0 + 16) ^ vxor));
            i32x2 b0 = *(const i32x2*)(vrow + (o1 ^ vxor));
            i32x2 b1 = *(const i32x2*)(vrow + ((o1 + 16) ^ vxor));
            i32x4 vb0; vb0[0]=a0[0]; vb0[1]=a0[1]; vb0[2]=a1[0]; vb0[3]=a1[1];
            i32x4 vb1; vb1[0]=b0[0]; vb1[1]=b0[1]; vb1[2]=b1[0]; vb1[3]=b1[1];
            __builtin_amdgcn_s_setprio(1);
            acc = __builtin_amdgcn_mfma_f32_32x32x16_bf16(
                __builtin_bit_cast(bf16x8, p0), __builtin_bit_cast(bf16x8, vb0), acc, 0, 0, 0);
            acc = __builtin_amdgcn_mfma_f32_32x32x16_bf16(
                __builtin_bit_cast(bf16x8, p1), __builtin_bit_cast(bf16x8, vb1), acc, 0, 0, 0);
            __builtin_amdgcn_s_setprio(0);
        }
        __syncthreads();
    }

    if (grp != 0) {
#pragma unroll
        for (int r = 0; r < 16; ++r) redacc[((grp - 1) * 16 + r) * 128 + tl] = acc[r];
        redden[(grp - 1) * 128 + tl] = den;
    }
    __syncthreads();
    if (grp == 0) {
#pragma unroll
        for (int r = 0; r < 16; ++r)
            acc[r] += redacc[r * 128 + tl] + redacc[(16 + r) * 128 + tl] + redacc[(32 + r) * 128 + tl];
        den += redden[tl] + redden[128 + tl] + redden[256 + tl];
        const float dfull = den + __shfl_xor(den, 32);
        if (hi == 0) invs[w * 32 + lo] = 1.f / dfull;
        float4 i0 = *(const float4*)&invs[w * 32 + 4 * hi];
        float4 i1 = *(const float4*)&invs[w * 32 + 8 + 4 * hi];
        float4 i2 = *(const float4*)&invs[w * 32 + 16 + 4 * hi];
        float4 i3 = *(const float4*)&invs[w * 32 + 24 + 4 * hi];
        float iv[16] = {i0.x,i0.y,i0.z,i0.w, i1.x,i1.y,i1.z,i1.w,
                        i2.x,i2.y,i2.z,i2.w, i3.x,i3.y,i3.z,i3.w};
        const int b = bh >> 3, h = bh & 7;
        unsigned short* cbase = ctxb + ((size_t)(b * SQL + qc * 64 + w * 32)) * 256 + h * 32 + lo;
#pragma unroll
        for (int r = 0; r < 16; ++r) {
            const int qr = (r & 3) + 8 * (r >> 2) + 4 * hi;
            cbase[(size_t)qr * 256] = bfu(acc[r] * iv[r]);
        }
    }
}

// ---------------- generic MFMA GEMM: 64x128 tile, single-buffer, 6 blocks/CU ----------------
template<int KSTRIDE, int KT, int NFULL, int RELU, int OUTF, int OUTB>
__global__ __launch_bounds__(256, 6) void k_gemm(
    const unsigned short* __restrict__ A, const unsigned short* __restrict__ Bt,
    const float* __restrict__ bias,
    float* __restrict__ outf, unsigned short* __restrict__ outb)
{
    __shared__ __align__(16) char As[8192];
    __shared__ __align__(16) char Bs[16384];
    const int t = threadIdx.x;
    const int lane = t & 63, w = t >> 6;
    const int lo = lane & 31, hi = lane >> 5;
    const int row0 = blockIdx.x * 64;
    const int col0 = blockIdx.y * 128;
    const int mr = (w & 1) * 32, nc = (w >> 1) * 64;
    f32x16 acc[2] = {};

    for (int kt = 0; kt < KT; ++kt) {
        const int k0 = kt * 64;
#pragma unroll
        for (int it = 0; it < 2; ++it) {
            const int idx = it * 256 + t;
            const int r = idx >> 3, g = idx & 7;
            glds16((const char*)(A + (size_t)(row0 + r) * KSTRIDE + k0) + ((g ^ (r & 7)) << 4),
                   As + it * 4096 + w * 1024 + lane * 16);
        }
#pragma unroll
        for (int it = 0; it < 4; ++it) {
            const int idx = it * 256 + t;
            const int r = idx >> 3, g = idx & 7;
            glds16((const char*)(Bt + (size_t)(col0 + r) * KSTRIDE + k0) + ((g ^ (r & 7)) << 4),
                   Bs + it * 4096 + w * 1024 + lane * 16);
        }
        __syncthreads();
        const int rA = mr + lo;
        const int rB = nc + lo;
#pragma unroll
        for (int s = 0; s < 4; ++s) {
            const int g = s * 2 + hi;
            bf16x8 fa  = *(const bf16x8*)(As + rA * 128 + ((g ^ (rA & 7)) << 4));
            bf16x8 fb0 = *(const bf16x8*)(Bs + rB * 128 + ((g ^ (rB & 7)) << 4));
            bf16x8 fb1 = *(const bf16x8*)(Bs + (rB + 32) * 128 + ((g ^ (rB & 7)) << 4));
            acc[0] = __builtin_amdgcn_mfma_f32_32x32x16_bf16(fa, fb0, acc[0], 0, 0, 0);
            acc[1] = __builtin_amdgcn_mfma_f32_32x32x16_bf16(fa, fb1, acc[1], 0, 0, 0);
        }
        __syncthreads();
    }
#pragma unroll
    for (int n = 0; n < 2; ++n) {
        const int c0 = col0 + nc + n * 32;
        const float bv = bias[c0 + lo];
#pragma unroll
        for (int r = 0; r < 16; ++r) {
            const int gr = row0 + mr + (r & 3) + 8 * (r >> 2) + 4 * hi;
            float vv = acc[n][r] + bv;
            if (RELU) vv = fmaxf(vv, 0.f);
            if (OUTF) outf[(size_t)gr * NFULL + c0 + lo] = vv;
            if (OUTB) outb[(size_t)gr * NFULL + c0 + lo] = bfu(vv);
        }
    }
}

// ---------------- fused residual + LayerNorm ----------------
template<int DUAL>
__global__ __launch_bounds__(256) void k_lnsum(
    const float* __restrict__ pa, const float* __restrict__ res,
    const float* __restrict__ g, const float* __restrict__ bt,
    float* __restrict__ outf, unsigned short* __restrict__ outb)
{
    const int row = blockIdx.x * 4 + (threadIdx.x >> 6);
    const int lane = threadIdx.x & 63;
    const size_t base = (size_t)row * 256;
    float4 v  = ((const float4*)(pa + base))[lane];
    float4 v3 = ((const float4*)(res + base))[lane];
    v.x += v3.x; v.y += v3.y; v.z += v3.z; v.w += v3.w;
    float s  = v.x + v.y + v.z + v.w;
    float ss = v.x * v.x + v.y * v.y + v.z * v.z + v.w * v.w;
#pragma unroll
    for (int off = 32; off; off >>= 1) { s += __shfl_xor(s, off); ss += __shfl_xor(ss, off); }
    const float mu = s * (1.f / 256.f);
    const float rstd = rsqrtf(ss * (1.f / 256.f) - mu * mu + LNEPS);
    const float4 gg = ((const float4*)g)[lane];
    const float4 bb = ((const float4*)bt)[lane];
    float4 o;
    o.x = (v.x - mu) * rstd * gg.x + bb.x;
    o.y = (v.y - mu) * rstd * gg.y + bb.y;
    o.z = (v.z - mu) * rstd * gg.z + bb.z;
    o.w = (v.w - mu) * rstd * gg.w + bb.w;
    ((float4*)(outf + base))[lane] = o;
    if (DUAL) {
        ushort4 ob; ob.x = bfu(o.x); ob.y = bfu(o.y); ob.z = bfu(o.z); ob.w = bfu(o.w);
        ((ushort4*)(outb + base))[lane] = ob;
    }
}

extern "C" void kernel_launch(void* const* d_in, const int* in_sizes, int n_in,
                              void* d_out, int out_size, void* d_ws, size_t ws_size,
                              hipStream_t stream) {
    const float* x   = (const float*)d_in[0];
    const float* wq  = (const float*)d_in[1];  const float* bq  = (const float*)d_in[2];
    const float* wk  = (const float*)d_in[3];  const float* bk  = (const float*)d_in[4];
    const float* wv  = (const float*)d_in[5];  const float* bv  = (const float*)d_in[6];
    const float* wo  = (const float*)d_in[7];  const float* wob = (const float*)d_in[8];
    const float* w1  = (const float*)d_in[9];  const float* b1  = (const float*)d_in[10];
    const float* w2  = (const float*)d_in[11]; const float* b2  = (const float*)d_in[12];
    const float* g1  = (const float*)d_in[13]; const float* bl1 = (const float*)d_in[14];
    const float* g2  = (const float*)d_in[15]; const float* bl2 = (const float*)d_in[16];

    char* ws = (char*)d_ws;
    unsigned short* xb    = (unsigned short*)(ws + B_XB);
    unsigned short* qb    = (unsigned short*)(ws + B_QB);
    unsigned short* kbuf  = (unsigned short*)(ws + B_KB);
    char*           vt    = (char*)(ws + B_VT);
    unsigned short* ctxb  = (unsigned short*)(ws + B_CTX);
    unsigned short* o1b   = (unsigned short*)(ws + B_O1B);
    float*          o1f   = (float*)(ws + B_O1F);
    unsigned short* mid   = (unsigned short*)(ws + B_MID);
    float*          c1    = (float*)(ws + B_MID);    // dead before mid written
    float*          c2    = (float*)(ws + B_C2);     // alias xb/qb (dead)
    unsigned short* wqkvT = (unsigned short*)(ws + B_WQKVT);
    unsigned short* woT   = (unsigned short*)(ws + B_WOT);
    unsigned short* w1T   = (unsigned short*)(ws + B_W1T);
    unsigned short* w2T   = (unsigned short*)(ws + B_W2T);
    float* bqkv = (float*)(ws + B_BQKV);
    unsigned int* hqp = (unsigned int*)(ws + B_HQ);
    unsigned int* hkp = (unsigned int*)(ws + B_HK);
    float* out  = (float*)d_out;

    k_packall<<<dim3(2819), dim3(256), 0, stream>>>(wq, wk, wv, wo, w1, w2, bq, bk, bv, x,
                                                    wqkvT, woT, w1T, w2T, bqkv, xb);
    k_qkv<<<dim3(128, 6), dim3(256), 0, stream>>>(xb, wqkvT, bqkv, qb, kbuf, vt, hqp, hkp);
    k_attn<<<dim3(1024), dim3(512), 0, stream>>>(qb, kbuf, vt, hqp, hkp, ctxb);
    k_gemm<256, 4, 256, 0, 1, 0><<<dim3(128, 2), dim3(256), 0, stream>>>(ctxb, woT, wob, c1, nullptr);
    k_lnsum<1><<<dim3(2048), dim3(256), 0, stream>>>(c1, x, g1, bl1, o1f, o1b);
    k_gemm<256, 4, 1024, 1, 0, 1><<<dim3(128, 8), dim3(256), 0, stream>>>(o1b, w1T, b1, nullptr, mid);
    k_gemm<1024, 16, 256, 0, 1, 0><<<dim3(128, 2), dim3(256), 0, stream>>>(mid, w2T, b2, c2, nullptr);
    k_lnsum<0><<<dim3(2048), dim3(256), 0, stream>>>(c2, o1f, g2, bl2, out, nullptr);
}